// Round 14
// baseline (289.857 us; speedup 1.0000x reference)
//
#include <hip/hip_runtime.h>
#include <math.h>

// Problem dims (fixed by reference)
#define BB 32
#define DD 256
#define TT 1024
#define KK 1024
#define NN (BB*TT)          // 32768 rows

#define BROWS 128           // rows per block (one block per CU)
#define NSTEP 32            // 2 code-chunks x 16 slices of 16 d

// ws layout (elements): float wsq[1024] @0 ; int counts[1024] @1024 ; float sse @2048

// wsq[k] = sum_d W[k,d]^2 (fp64 accumulate, round once). Zeroes counts+sse.
__global__ void prep_kernel(const float* __restrict__ W, float* __restrict__ wsq,
                            int* __restrict__ counts, float* __restrict__ sse) {
    const int k = blockIdx.x;          // 1024 blocks, 64 threads
    const int lane = threadIdx.x;
    const float4 v = ((const float4*)(W + (size_t)k * DD))[lane];
    double s = (double)v.x * v.x + (double)v.y * v.y + (double)v.z * v.z + (double)v.w * v.w;
    #pragma unroll
    for (int m = 32; m > 0; m >>= 1) s += __shfl_down(s, m);
    if (lane == 0) wsq[k] = (float)s;
    if (blockIdx.x < 16) counts[blockIdx.x * 64 + lane] = 0;
    if (blockIdx.x == 0 && lane == 0) *sse = 0.0f;
}

// async global->LDS, 16B/lane; LDS dest = wave-uniform base + lane*16 (linear).
__device__ __forceinline__ void gl_lds16(const float* g, void* l) {
    __builtin_amdgcn_global_load_lds((const __attribute__((address_space(1))) void*)g,
                                     (__attribute__((address_space(3))) void*)l, 16, 0, 0);
}

// Fused VQ. 512 thr = 8 waves, 1 block/CU (grid 256). R12 structure + T4:
// TRIPLE-buffered staging (2 steps ahead) with counted vmcnt + raw s_barrier —
// the barrier never drains the current step's staging (R12's __syncthreads did
// vmcnt(0) every step). Steady-state loop vmem = EXACTLY 5 gl_lds/thread/step
// (wsq preloaded to regs in prologue — R13 lesson: any in-loop vmem consumption
// drains younger staging).
//  - zst[3][16 d][128 r] (3x8 KB): zf reads wave-broadcast.
//  - wst[3] slot-major [j(8)][q(4)][lane(64)] (3x32 KB): conflict-free b128
//    (R12: SQ_LDS_BANK_CONFLICT == 0). gl_lds linear dest, inverse-map source.
// dist mirrors np: s1 = fl(rowsq+wsq); v = fmaf(-2, dot, s1). Per-(row,code)
// dot: single sequential fmaf chain d=0..255 (t asc -> q asc -> dp asc) —
// bitwise same chain as R1-R13 (validated absmax==0.0 11x). DO NOT reorder.
// acc static-indexed only (rule #20); q-loop rolled (R4 lesson).
__global__ __launch_bounds__(512, 2) void vq_fused_kernel(
    const float* __restrict__ z, const float* __restrict__ W,
    const float* __restrict__ wsq, float* __restrict__ out,
    int* __restrict__ counts, float* __restrict__ sse)
{
    __shared__ float zst[3][16 * 128];   // 24 KB (zst[0] = idx scratch at end)
    __shared__ float wst[3][16 * 512];   // 96 KB (wst[0] = sse scratch at end;
                                         //        wst[2] = rowsq scratch pre-loop)
    __shared__ float rsql[128];
    const int tid = threadIdx.x;
    const int wid = tid >> 6, lane = tid & 63;
    const int row0 = blockIdx.x * BROWS;
    const int b = row0 >> 10, t0 = row0 & 1023;
    const size_t bbase = (size_t)b * DD * TT;
    const float* zbase = z + bbase + t0;

    // ---- prologue staging: steps 0 and 1 into bufs 0,1 (5 gl_lds each)
    #pragma unroll
    for (int pt = 0; pt < 2; ++pt) {
        const float* wc = W + (size_t)0 * DD + pt * 16;   // ch=0, sl=pt
        char* dw = (char*)&wst[pt][0];
        #pragma unroll
        for (int k = 0; k < 4; ++k) {
            const int m = k * 512 + tid;                  // 16B slot index
            const int j = m >> 8, q = (m >> 6) & 3, l = m & 63;
            gl_lds16(wc + (size_t)(j * 64 + l) * DD + q * 4, dw + (size_t)m * 16);
        }
        const int d = tid >> 5, r4 = (tid & 31) * 4;
        gl_lds16(zbase + (size_t)(pt * 16 + d) * TT + r4,
                 (char*)&zst[pt][0] + (size_t)tid * 16);
    }

    // ---- rowsq (R12 form): per row 4 fp64 64-d chains, tree (p0+p1)+(p2+p3)
    {
        double* pscr = (double*)&wst[2][0];        // 4 KB scratch (buf2 staged at t=0)
        const int rr = tid & 127, g = tid >> 7;
        const float* zp = zbase + (size_t)g * 64 * TT + rr;
        double s = 0.0;
        #pragma unroll 4
        for (int d = 0; d < 64; ++d) { float v = zp[(size_t)d * TT]; s += (double)v * v; }
        pscr[g * 128 + rr] = s;
        __syncthreads();
        if (tid < 128)
            rsql[tid] = (float)((pscr[tid] + pscr[128 + tid]) + (pscr[256 + tid] + pscr[384 + tid]));
    }

    // ---- preload wsq for both chunks (16 regs; no in-loop global loads)
    float wq0[8], wq1[8];
    #pragma unroll
    for (int j = 0; j < 8; ++j) {
        wq0[j] = wsq[j * 64 + lane];
        wq1[j] = wsq[512 + j * 64 + lane];
    }

    // drain everything (prologue staging + rowsq + wq), then barrier: bufs 0,1
    // ready, loop starts with vmcnt==0.
    asm volatile("s_waitcnt vmcnt(0)" ::: "memory");
    __syncthreads();

    float minv[16]; int mini[16];
    #pragma unroll
    for (int i = 0; i < 16; ++i) { minv[i] = 3.4e38f; mini[i] = 0; }
    float acc[16][8];

    for (int t = 0; t < NSTEP; ++t) {
        const int sl = t & 15, h = t % 3;
        // issue staging for step t+2 into buf (t+2)%3 (last read at step t-1;
        // barrier at end of t-1 precedes this issue)
        if (t + 2 < NSTEP) {
            const int tn = t + 2, chn = tn >> 4, sln = tn & 15, hn = tn % 3;
            const float* wc = W + (size_t)(chn * 512) * DD + sln * 16;
            char* dw = (char*)&wst[hn][0];
            #pragma unroll
            for (int k = 0; k < 4; ++k) {
                const int m = k * 512 + tid;
                const int j = m >> 8, q = (m >> 6) & 3, l = m & 63;
                gl_lds16(wc + (size_t)(j * 64 + l) * DD + q * 4, dw + (size_t)m * 16);
            }
            const int d = tid >> 5, r4 = (tid & 31) * 4;
            gl_lds16(zbase + (size_t)(sln * 16 + d) * TT + r4,
                     (char*)&zst[hn][0] + (size_t)tid * 16);
        }
        if (sl == 0) {
            #pragma unroll
            for (int i = 0; i < 16; ++i)
                #pragma unroll
                for (int j = 0; j < 8; ++j) acc[i][j] = 0.0f;
        }
        // compute: 4 q-groups x (8 wf conflict-free b128 + 4 zf broadcast b128
        // + 512 fmaf/thread)
        const float*  zb  = &zst[h][0];
        const float4* wb4 = (const float4*)&wst[h][0];
        __builtin_amdgcn_s_setprio(1);
        #pragma clang loop unroll(disable)
        for (int q = 0; q < 4; ++q) {
            const float4* wp = wb4 + q * 64 + lane;       // + j*256 (imm j*4096B)
            float4 wf[8];
            #pragma unroll
            for (int j = 0; j < 8; ++j) wf[j] = wp[j * 256];
            #pragma unroll
            for (int dp = 0; dp < 4; ++dp) {
                const float4* zp4 = (const float4*)(zb + (q * 4 + dp) * 128 + wid * 16);
                const float4 za = zp4[0], zc = zp4[1], ze = zp4[2], zg = zp4[3];
                #pragma unroll
                for (int j = 0; j < 8; ++j) {
                    const float wv = dp == 0 ? wf[j].x : dp == 1 ? wf[j].y
                                   : dp == 2 ? wf[j].z : wf[j].w;
                    acc[0][j]  = fmaf(za.x, wv, acc[0][j]);
                    acc[1][j]  = fmaf(za.y, wv, acc[1][j]);
                    acc[2][j]  = fmaf(za.z, wv, acc[2][j]);
                    acc[3][j]  = fmaf(za.w, wv, acc[3][j]);
                    acc[4][j]  = fmaf(zc.x, wv, acc[4][j]);
                    acc[5][j]  = fmaf(zc.y, wv, acc[5][j]);
                    acc[6][j]  = fmaf(zc.z, wv, acc[6][j]);
                    acc[7][j]  = fmaf(zc.w, wv, acc[7][j]);
                    acc[8][j]  = fmaf(ze.x, wv, acc[8][j]);
                    acc[9][j]  = fmaf(ze.y, wv, acc[9][j]);
                    acc[10][j] = fmaf(ze.z, wv, acc[10][j]);
                    acc[11][j] = fmaf(ze.w, wv, acc[11][j]);
                    acc[12][j] = fmaf(zg.x, wv, acc[12][j]);
                    acc[13][j] = fmaf(zg.y, wv, acc[13][j]);
                    acc[14][j] = fmaf(zg.z, wv, acc[14][j]);
                    acc[15][j] = fmaf(zg.w, wv, acc[15][j]);
                }
            }
        }
        __builtin_amdgcn_s_setprio(0);
        if (t == 15) {
            // score + running argmin, chunk 0 (codes j*64+lane, j asc; strict <)
            #pragma unroll
            for (int i = 0; i < 16; ++i) {
                const float rs = rsql[wid * 16 + i];
                #pragma unroll
                for (int j = 0; j < 8; ++j) {
                    const float s1 = rs + wq0[j];            // rounding 1 (np A+B)
                    const float v = fmaf(-2.0f, acc[i][j], s1); // rounding 2
                    if (v < minv[i]) { minv[i] = v; mini[i] = j * 64 + lane; }
                }
            }
        } else if (t == 31) {
            // chunk 1
            #pragma unroll
            for (int i = 0; i < 16; ++i) {
                const float rs = rsql[wid * 16 + i];
                #pragma unroll
                for (int j = 0; j < 8; ++j) {
                    const float s1 = rs + wq1[j];
                    const float v = fmaf(-2.0f, acc[i][j], s1);
                    if (v < minv[i]) { minv[i] = v; mini[i] = 512 + j * 64 + lane; }
                }
            }
        }
        // T4 counted wait: drain step-(t+1)'s staging (issued at t-1, >=1 full
        // step old -> ~free); leave this step's 5 fresh loads in flight.
        if (t + 2 < NSTEP) { asm volatile("s_waitcnt vmcnt(5)" ::: "memory"); }
        else               { asm volatile("s_waitcnt vmcnt(0)" ::: "memory"); }
        __builtin_amdgcn_s_barrier();
    }

    // ---- per-wave argmin reduce over 64 lanes (explicit index tie-break -> lowest)
    __syncthreads();                     // compute done; zst/wst become scratch
    int* idxs = (int*)&zst[0][0];        // 128 ints
    float* ssescr = (float*)&wst[0][0];  // 8 floats
    #pragma unroll
    for (int i = 0; i < 16; ++i) {
        float v = minv[i]; int ix = mini[i];
        #pragma unroll
        for (int m = 1; m < 64; m <<= 1) {
            float ov = __shfl_xor(v, m);
            int   oi = __shfl_xor(ix, m);
            if (ov < v || (ov == v && oi < ix)) { v = ov; ix = oi; }
        }
        if (lane == 0) {
            idxs[wid * 16 + i] = ix;
            atomicAdd(&counts[ix], 1);
        }
    }
    __syncthreads();

    // ---- fused gather / straight-through / SSE over 128 rows x 256 d
    const int tg = tid & 31;       // 32 t-groups of 4 rows
    const int dg = tid >> 5;       // 16 d-groups of 16
    const int t4 = tg * 4;
    int ixs[4];
    #pragma unroll
    for (int m = 0; m < 4; ++m) ixs[m] = idxs[t4 + m];
    float ssel = 0.0f;
    #pragma unroll
    for (int k4 = 0; k4 < 4; ++k4) {
        const int d0 = dg * 16 + k4 * 4;
        float wr[4][4];
        #pragma unroll
        for (int m = 0; m < 4; ++m) {
            float4 wv = *(const float4*)(W + (size_t)ixs[m] * DD + d0);
            wr[m][0] = wv.x; wr[m][1] = wv.y; wr[m][2] = wv.z; wr[m][3] = wv.w;
        }
        #pragma unroll
        for (int dd = 0; dd < 4; ++dd) {
            const int d = d0 + dd;
            const size_t base = bbase + (size_t)d * TT + t0 + t4;
            float4 zv = *(const float4*)(z + base);
            float e0 = wr[0][dd] - zv.x, e1 = wr[1][dd] - zv.y;
            float e2 = wr[2][dd] - zv.z, e3 = wr[3][dd] - zv.w;
            float4 o;
            o.x = zv.x + e0; o.y = zv.y + e1; o.z = zv.z + e2; o.w = zv.w + e3;
            *(float4*)(out + base) = o;
            ssel += (e0 * e0 + e1 * e1) + (e2 * e2 + e3 * e3);
        }
    }
    #pragma unroll
    for (int m = 32; m > 0; m >>= 1) ssel += __shfl_down(ssel, m);
    if (lane == 0) ssescr[wid] = ssel;
    __syncthreads();
    if (tid == 0)
        atomicAdd(sse, ((ssescr[0] + ssescr[1]) + (ssescr[2] + ssescr[3]))
                     + ((ssescr[4] + ssescr[5]) + (ssescr[6] + ssescr[7])));
}

// reg_loss = 1.25 * sse / numel ; perplexity = exp(-sum p*log(p+1e-10))
__global__ void finalize_kernel(const int* __restrict__ counts, const float* __restrict__ sse,
                                float* __restrict__ out) {
    float s = 0.0f;
    for (int k = threadIdx.x; k < KK; k += 256) {
        float p = (float)counts[k] / (float)NN;
        s += p * logf(p + 1e-10f);
    }
    #pragma unroll
    for (int m = 32; m > 0; m >>= 1) s += __shfl_down(s, m);
    __shared__ float wsum[4];
    if ((threadIdx.x & 63) == 0) wsum[threadIdx.x >> 6] = s;
    __syncthreads();
    if (threadIdx.x == 0) {
        float ent = (wsum[0] + wsum[1]) + (wsum[2] + wsum[3]);
        out[(size_t)BB * DD * TT]     = 1.25f * (*sse) / (float)(BB * DD * TT);
        out[(size_t)BB * DD * TT + 1] = expf(-ent);
    }
}

extern "C" void kernel_launch(void* const* d_in, const int* in_sizes, int n_in,
                              void* d_out, int out_size, void* d_ws, size_t ws_size,
                              hipStream_t stream) {
    const float* z = (const float*)d_in[0];   // (32, 256, 1024) fp32
    const float* W = (const float*)d_in[1];   // (1024, 256) fp32
    float* out = (float*)d_out;               // 8388608 + 2 fp32

    float* wsq    = (float*)d_ws;
    int*   counts = (int*)(wsq + 1024);
    float* sse    = (float*)(counts + 1024);

    prep_kernel<<<1024, 64, 0, stream>>>(W, wsq, counts, sse);
    vq_fused_kernel<<<NN / BROWS, 512, 0, stream>>>(z, W, wsq, out, counts, sse);
    finalize_kernel<<<1, 256, 0, stream>>>(counts, sse, out);
}

// Round 15
// 263.081 us; speedup vs baseline: 1.1018x; 1.1018x over previous
//
#include <hip/hip_runtime.h>
#include <math.h>

// Problem dims (fixed by reference)
#define BB 32
#define DD 256
#define TT 1024
#define KK 1024
#define NN (BB*TT)          // 32768 rows

#define BROWS 64            // rows per block -> grid 512 = 2 blocks/CU (TLP)
#define NSTEP 32            // 2 code-chunks x 16 slices of 16 d

// ws layout (elements): float wsq[1024] @0 ; int counts[1024] @1024 ; float sse @2048

// wsq[k] = sum_d W[k,d]^2 (fp64 accumulate, round once). Zeroes counts+sse.
__global__ void prep_kernel(const float* __restrict__ W, float* __restrict__ wsq,
                            int* __restrict__ counts, float* __restrict__ sse) {
    const int k = blockIdx.x;          // 1024 blocks, 64 threads
    const int lane = threadIdx.x;
    const float4 v = ((const float4*)(W + (size_t)k * DD))[lane];
    double s = (double)v.x * v.x + (double)v.y * v.y + (double)v.z * v.z + (double)v.w * v.w;
    #pragma unroll
    for (int m = 32; m > 0; m >>= 1) s += __shfl_down(s, m);
    if (lane == 0) wsq[k] = (float)s;
    if (blockIdx.x < 16) counts[blockIdx.x * 64 + lane] = 0;
    if (blockIdx.x == 0 && lane == 0) *sse = 0.0f;
}

// async global->LDS, 16B/lane; LDS dest = wave-uniform base + lane*16 (linear).
__device__ __forceinline__ void gl_lds16(const float* g, void* l) {
    __builtin_amdgcn_global_load_lds((const __attribute__((address_space(1))) void*)g,
                                     (__attribute__((address_space(3))) void*)l, 16, 0, 0);
}

// Fused VQ — R12's exact instruction mix at 2 independent blocks/CU.
// 256 thr = 4 waves; block owns 64 rows; wave wid owns rows wid*16..+15; lane
// owns codes {j*64+lane} of the current 512-code chunk -> per-thread 16x8 acc
// (21.3 fmaf/LDS-read). Two co-resident blocks overlap each other's barrier
// stalls (R2->R3 mechanism, m114 overlap).
//  - zst[2][16 d][64 r] (2x4 KB, gl_lds direct): zf reads wave-broadcast.
//  - wst[2] slot-major [j(8)][q(4)][lane(64)] (2x32 KB): for fixed (j,q) lanes
//    read stride-16B -> conflict-free b128 (R12: SQ_LDS_BANK_CONFLICT == 0).
//    gl_lds linear dest + inverse-mapped source (W is L2-resident).
// dist mirrors np: s1 = fl(rowsq+wsq); v = fmaf(-2, dot, s1). Per-(row,code)
// dot: single sequential fmaf chain d=0..255 (t asc -> q asc -> dp asc) —
// bitwise same chain as R1-R14 (validated absmax==0.0 12x). DO NOT reorder.
// acc static-indexed only (rule #20); q-loop rolled (R4 lesson); no in-loop
// vmem consumed near staging except wq at sl==0 (R12-proven; R13 lesson).
__global__ __launch_bounds__(256, 2) void vq_fused_kernel(
    const float* __restrict__ z, const float* __restrict__ W,
    const float* __restrict__ wsq, float* __restrict__ out,
    int* __restrict__ counts, float* __restrict__ sse)
{
    __shared__ float zst[2][16 * 64];    // 8 KB (zst[0] idx scratch at end;
                                         //       zst[1] rowsq scratch pre-loop)
    __shared__ float wst[2][16 * 512];   // 64 KB (wst[0] sse scratch at end)
    __shared__ float rsql[64];
    const int tid = threadIdx.x;
    const int wid = tid >> 6, lane = tid & 63;
    const int row0 = blockIdx.x * BROWS;
    const int b = row0 >> 10, t0 = row0 & 1023;
    const size_t bbase = (size_t)b * DD * TT;
    const float* zbase = z + bbase + t0;

    // ---- prologue staging for step 0 (ch=0, sl=0)
    {
        char* dw = (char*)&wst[0][0];
        #pragma unroll
        for (int k = 0; k < 8; ++k) {
            const int m = k * 256 + tid;                  // 16B slot index
            const int j = m >> 8, q = (m >> 6) & 3, l = m & 63;
            gl_lds16(W + (size_t)(j * 64 + l) * DD + q * 4, dw + (size_t)m * 16);
        }
        const int d = tid >> 4, r4 = (tid & 15) * 4;
        gl_lds16(zbase + (size_t)d * TT + r4, (char*)&zst[0][0] + (size_t)tid * 16);
    }

    // ---- rowsq: per row 4 fp64 64-d chains, tree (p0+p1)+(p2+p3) (validated)
    {
        double* pscr = (double*)&zst[1][0];        // 2 KB scratch (zst[1] free pre-loop)
        const int rr = tid & 63, g = tid >> 6;
        const float* zp = zbase + (size_t)g * 64 * TT + rr;
        double s = 0.0;
        #pragma unroll 4
        for (int d = 0; d < 64; ++d) { float v = zp[(size_t)d * TT]; s += (double)v * v; }
        pscr[g * 64 + rr] = s;
        __syncthreads();
        if (tid < 64)
            rsql[tid] = (float)((pscr[tid] + pscr[64 + tid]) + (pscr[128 + tid] + pscr[192 + tid]));
    }

    float minv[16]; int mini[16];
    #pragma unroll
    for (int i = 0; i < 16; ++i) { minv[i] = 3.4e38f; mini[i] = 0; }
    float acc[16][8];

    for (int t = 0; t < NSTEP; ++t) {
        const int ch = t >> 4, sl = t & 15, h = t & 1;
        __syncthreads();   // drains vmcnt/lgkm: buffers[h] (staged at t-1) ready;
                           // at t=0 also fences rowsq scratch + rsql write
        // issue step t+1 staging NOW; lands during compute below
        if (t + 1 < NSTEP) {
            const int tn = t + 1, chn = tn >> 4, sln = tn & 15;
            const float* wc = W + (size_t)(chn * 512) * DD + sln * 16;
            char* dw = (char*)&wst[tn & 1][0];
            #pragma unroll
            for (int k = 0; k < 8; ++k) {
                const int m = k * 256 + tid;
                const int j = m >> 8, q = (m >> 6) & 3, l = m & 63;
                gl_lds16(wc + (size_t)(j * 64 + l) * DD + q * 4, dw + (size_t)m * 16);
            }
            const int d = tid >> 4, r4 = (tid & 15) * 4;
            gl_lds16(zbase + (size_t)(sln * 16 + d) * TT + r4,
                     (char*)&zst[tn & 1][0] + (size_t)tid * 16);
        }
        if (sl == 0) {
            #pragma unroll
            for (int i = 0; i < 16; ++i)
                #pragma unroll
                for (int j = 0; j < 8; ++j) acc[i][j] = 0.0f;
        }
        // compute: 4 q-groups x (8 wf conflict-free b128 + 4 zf broadcast b128
        // + 512 fmaf/thread)
        const float*  zb  = &zst[h][0];
        const float4* wb4 = (const float4*)&wst[h][0];
        __builtin_amdgcn_s_setprio(1);
        #pragma clang loop unroll(disable)
        for (int q = 0; q < 4; ++q) {
            const float4* wp = wb4 + q * 64 + lane;       // + j*256 (imm j*4096B)
            float4 wf[8];
            #pragma unroll
            for (int j = 0; j < 8; ++j) wf[j] = wp[j * 256];
            #pragma unroll
            for (int dp = 0; dp < 4; ++dp) {
                const float4* zp4 = (const float4*)(zb + (q * 4 + dp) * 64 + wid * 16);
                const float4 za = zp4[0], zc = zp4[1], ze = zp4[2], zg = zp4[3];
                #pragma unroll
                for (int j = 0; j < 8; ++j) {
                    const float wv = dp == 0 ? wf[j].x : dp == 1 ? wf[j].y
                                   : dp == 2 ? wf[j].z : wf[j].w;
                    acc[0][j]  = fmaf(za.x, wv, acc[0][j]);
                    acc[1][j]  = fmaf(za.y, wv, acc[1][j]);
                    acc[2][j]  = fmaf(za.z, wv, acc[2][j]);
                    acc[3][j]  = fmaf(za.w, wv, acc[3][j]);
                    acc[4][j]  = fmaf(zc.x, wv, acc[4][j]);
                    acc[5][j]  = fmaf(zc.y, wv, acc[5][j]);
                    acc[6][j]  = fmaf(zc.z, wv, acc[6][j]);
                    acc[7][j]  = fmaf(zc.w, wv, acc[7][j]);
                    acc[8][j]  = fmaf(ze.x, wv, acc[8][j]);
                    acc[9][j]  = fmaf(ze.y, wv, acc[9][j]);
                    acc[10][j] = fmaf(ze.z, wv, acc[10][j]);
                    acc[11][j] = fmaf(ze.w, wv, acc[11][j]);
                    acc[12][j] = fmaf(zg.x, wv, acc[12][j]);
                    acc[13][j] = fmaf(zg.y, wv, acc[13][j]);
                    acc[14][j] = fmaf(zg.z, wv, acc[14][j]);
                    acc[15][j] = fmaf(zg.w, wv, acc[15][j]);
                }
            }
        }
        __builtin_amdgcn_s_setprio(0);
        if (sl == 15) {
            // score + running argmin (thread codes j*64+lane: j asc = code asc;
            // strict < -> first-min like np.argmin)
            float wq[8];
            #pragma unroll
            for (int j = 0; j < 8; ++j) wq[j] = wsq[ch * 512 + j * 64 + lane];
            #pragma unroll
            for (int i = 0; i < 16; ++i) {
                const float rs = rsql[wid * 16 + i];
                #pragma unroll
                for (int j = 0; j < 8; ++j) {
                    const float s1 = rs + wq[j];             // rounding 1 (np A+B)
                    const float v = fmaf(-2.0f, acc[i][j], s1); // rounding 2 (np (A+B)-2P)
                    if (v < minv[i]) { minv[i] = v; mini[i] = ch * 512 + j * 64 + lane; }
                }
            }
        }
    }

    // ---- per-wave argmin reduce over 64 lanes (explicit index tie-break -> lowest)
    __syncthreads();                     // compute done; zst/wst become scratch
    int* idxs = (int*)&zst[0][0];        // 64 ints
    float* ssescr = (float*)&wst[0][0];  // 4 floats
    #pragma unroll
    for (int i = 0; i < 16; ++i) {
        float v = minv[i]; int ix = mini[i];
        #pragma unroll
        for (int m = 1; m < 64; m <<= 1) {
            float ov = __shfl_xor(v, m);
            int   oi = __shfl_xor(ix, m);
            if (ov < v || (ov == v && oi < ix)) { v = ov; ix = oi; }
        }
        if (lane == 0) {
            idxs[wid * 16 + i] = ix;
            atomicAdd(&counts[ix], 1);
        }
    }
    __syncthreads();

    // ---- fused gather / straight-through / SSE over this block's 64 rows x 256 d
    const int tg = tid & 15;       // 16 t-groups of 4 rows
    const int dg = tid >> 4;       // 16 d-groups of 16
    const int t4 = tg * 4;
    int ixs[4];
    #pragma unroll
    for (int m = 0; m < 4; ++m) ixs[m] = idxs[t4 + m];
    float ssel = 0.0f;
    #pragma unroll
    for (int k4 = 0; k4 < 4; ++k4) {
        const int d0 = dg * 16 + k4 * 4;
        float wr[4][4];
        #pragma unroll
        for (int m = 0; m < 4; ++m) {
            float4 wv = *(const float4*)(W + (size_t)ixs[m] * DD + d0);
            wr[m][0] = wv.x; wr[m][1] = wv.y; wr[m][2] = wv.z; wr[m][3] = wv.w;
        }
        #pragma unroll
        for (int dd = 0; dd < 4; ++dd) {
            const int d = d0 + dd;
            const size_t base = bbase + (size_t)d * TT + t0 + t4;
            float4 zv = *(const float4*)(z + base);
            float e0 = wr[0][dd] - zv.x, e1 = wr[1][dd] - zv.y;
            float e2 = wr[2][dd] - zv.z, e3 = wr[3][dd] - zv.w;
            float4 o;
            o.x = zv.x + e0; o.y = zv.y + e1; o.z = zv.z + e2; o.w = zv.w + e3;
            *(float4*)(out + base) = o;
            ssel += (e0 * e0 + e1 * e1) + (e2 * e2 + e3 * e3);
        }
    }
    #pragma unroll
    for (int m = 32; m > 0; m >>= 1) ssel += __shfl_down(ssel, m);
    if (lane == 0) ssescr[wid] = ssel;
    __syncthreads();
    if (tid == 0) atomicAdd(sse, (ssescr[0] + ssescr[1]) + (ssescr[2] + ssescr[3]));
}

// reg_loss = 1.25 * sse / numel ; perplexity = exp(-sum p*log(p+1e-10))
__global__ void finalize_kernel(const int* __restrict__ counts, const float* __restrict__ sse,
                                float* __restrict__ out) {
    float s = 0.0f;
    for (int k = threadIdx.x; k < KK; k += 256) {
        float p = (float)counts[k] / (float)NN;
        s += p * logf(p + 1e-10f);
    }
    #pragma unroll
    for (int m = 32; m > 0; m >>= 1) s += __shfl_down(s, m);
    __shared__ float wsum[4];
    if ((threadIdx.x & 63) == 0) wsum[threadIdx.x >> 6] = s;
    __syncthreads();
    if (threadIdx.x == 0) {
        float ent = (wsum[0] + wsum[1]) + (wsum[2] + wsum[3]);
        out[(size_t)BB * DD * TT]     = 1.25f * (*sse) / (float)(BB * DD * TT);
        out[(size_t)BB * DD * TT + 1] = expf(-ent);
    }
}

extern "C" void kernel_launch(void* const* d_in, const int* in_sizes, int n_in,
                              void* d_out, int out_size, void* d_ws, size_t ws_size,
                              hipStream_t stream) {
    const float* z = (const float*)d_in[0];   // (32, 256, 1024) fp32
    const float* W = (const float*)d_in[1];   // (1024, 256) fp32
    float* out = (float*)d_out;               // 8388608 + 2 fp32

    float* wsq    = (float*)d_ws;
    int*   counts = (int*)(wsq + 1024);
    float* sse    = (float*)(counts + 1024);

    prep_kernel<<<1024, 64, 0, stream>>>(W, wsq, counts, sse);
    vq_fused_kernel<<<NN / BROWS, 256, 0, stream>>>(z, W, wsq, out, counts, sse);
    finalize_kernel<<<1, 256, 0, stream>>>(counts, sse, out);
}

// Round 16
// 227.905 us; speedup vs baseline: 1.2718x; 1.1543x over previous
//
#include <hip/hip_runtime.h>
#include <math.h>

// Problem dims (fixed by reference)
#define BB 32
#define DD 256
#define TT 1024
#define KK 1024
#define NN (BB*TT)          // 32768 rows

#define BROWS 128           // rows per block (one block per CU)
#define NSTEP 32            // 2 code-chunks x 16 slices of 16 d

// ws layout (elements): float wsq[1024] @0 ; int counts[1024] @1024 ; float sse @2048

// wsq[k] = sum_d W[k,d]^2 (fp64 accumulate, round once). Zeroes counts+sse.
__global__ void prep_kernel(const float* __restrict__ W, float* __restrict__ wsq,
                            int* __restrict__ counts, float* __restrict__ sse) {
    const int k = blockIdx.x;          // 1024 blocks, 64 threads
    const int lane = threadIdx.x;
    const float4 v = ((const float4*)(W + (size_t)k * DD))[lane];
    double s = (double)v.x * v.x + (double)v.y * v.y + (double)v.z * v.z + (double)v.w * v.w;
    #pragma unroll
    for (int m = 32; m > 0; m >>= 1) s += __shfl_down(s, m);
    if (lane == 0) wsq[k] = (float)s;
    if (blockIdx.x < 16) counts[blockIdx.x * 64 + lane] = 0;
    if (blockIdx.x == 0 && lane == 0) *sse = 0.0f;
}

// async global->LDS, 16B/lane; LDS dest = wave-uniform base + lane*16 (linear).
__device__ __forceinline__ void gl_lds16(const float* g, void* l) {
    __builtin_amdgcn_global_load_lds((const __attribute__((address_space(1))) void*)g,
                                     (__attribute__((address_space(3))) void*)l, 16, 0, 0);
}

// Fused VQ — the R12 optimum (229.0 us total, validated absmax==0.0).
// 512 thr = 8 waves, 1 block/CU (grid 256), 2 waves/SIMD.
// Tile: wave wid owns rows wid*16..+15; lane owns codes {j*64+lane} of the
// current 512-code chunk -> per-thread 16x8 acc (21.3 fmaf/LDS-read).
//  - zst[2][16 d][128 r] (2x8 KB, gl_lds direct): zf reads wave-broadcast.
//  - wst[2] slot-major [j(8)][q(4)][lane(64)] (2x32 KB): for fixed (j,q) lanes
//    read stride-16B -> CONFLICT-FREE b128 (measured SQ_LDS_BANK_CONFLICT==0);
//    address = one base (q*64+lane) + immediate j*4096B. gl_lds linear dest +
//    inverse-mapped source (W is L2-resident; no HBM cost).
// dist mirrors np: s1 = fl(rowsq+wsq); v = fmaf(-2, dot, s1). Per-(row,code)
// dot: single sequential fmaf chain d=0..255 (t asc -> q asc -> dp asc) —
// bitwise-matches BLAS k-order; validated absmax==0.0 in R1-R15. DO NOT
// reorder. acc static-indexed only (rule #20); q-loop rolled (R4 lesson).
// Schedule lessons locked in: no in-loop vmem consumption except wq at sl==15
// (R13); no deeper buffering (R14 spill); no smaller blocks (R15 staging tax).
__global__ __launch_bounds__(512, 2) void vq_fused_kernel(
    const float* __restrict__ z, const float* __restrict__ W,
    const float* __restrict__ wsq, float* __restrict__ out,
    int* __restrict__ counts, float* __restrict__ sse)
{
    __shared__ float zst[2][16 * 128];   // 16 KB (zst[0] reused as idx scratch at end)
    __shared__ float wst[2][16 * 512];   // 64 KB (wst[0] reused as sse scratch at end)
    __shared__ float rsql[128];
    const int tid = threadIdx.x;
    const int wid = tid >> 6, lane = tid & 63;
    const int row0 = blockIdx.x * BROWS;
    const int b = row0 >> 10, t0 = row0 & 1023;
    const size_t bbase = (size_t)b * DD * TT;
    const float* zbase = z + bbase + t0;

    // ---- prologue staging for step 0 (ch=0, sl=0); latency hides under rowsq
    {
        char* dw = (char*)&wst[0][0];
        #pragma unroll
        for (int k = 0; k < 4; ++k) {
            const int m = k * 512 + tid;                  // 16B slot index
            const int j = m >> 8, q = (m >> 6) & 3, l = m & 63;
            gl_lds16(W + (size_t)(j * 64 + l) * DD + q * 4, dw + (size_t)m * 16);
        }
        const int d = tid >> 5, r4 = (tid & 31) * 4;
        gl_lds16(zbase + (size_t)d * TT + r4, (char*)&zst[0][0] + (size_t)tid * 16);
    }

    // ---- rowsq: per row 4 fp64 64-d chains, tree (p0+p1)+(p2+p3) (validated form)
    {
        double* pscr = (double*)&zst[1][0];        // 4 KB scratch (zst[1] free pre-loop)
        const int rr = tid & 127, g = tid >> 7;
        const float* zp = zbase + (size_t)g * 64 * TT + rr;
        double s = 0.0;
        #pragma unroll 4
        for (int d = 0; d < 64; ++d) { float v = zp[(size_t)d * TT]; s += (double)v * v; }
        pscr[g * 128 + rr] = s;
        __syncthreads();
        if (tid < 128)
            rsql[tid] = (float)((pscr[tid] + pscr[128 + tid]) + (pscr[256 + tid] + pscr[384 + tid]));
    }

    float minv[16]; int mini[16];
    #pragma unroll
    for (int i = 0; i < 16; ++i) { minv[i] = 3.4e38f; mini[i] = 0; }
    float acc[16][8];

    for (int t = 0; t < NSTEP; ++t) {
        const int ch = t >> 4, sl = t & 15, h = t & 1;
        __syncthreads();   // drains vmcnt/lgkm: buffers[h] (staged at t-1) ready;
                           // at t=0 also fences rowsq scratch in zst[1]
        // issue step t+1 staging NOW; lands during ~4096 cyc of compute below
        if (t + 1 < NSTEP) {
            const int tn = t + 1, chn = tn >> 4, sln = tn & 15;
            const float* wc = W + (size_t)(chn * 512) * DD + sln * 16;
            char* dw = (char*)&wst[tn & 1][0];
            #pragma unroll
            for (int k = 0; k < 4; ++k) {
                const int m = k * 512 + tid;
                const int j = m >> 8, q = (m >> 6) & 3, l = m & 63;
                gl_lds16(wc + (size_t)(j * 64 + l) * DD + q * 4, dw + (size_t)m * 16);
            }
            const int d = tid >> 5, r4 = (tid & 31) * 4;
            gl_lds16(zbase + (size_t)(sln * 16 + d) * TT + r4,
                     (char*)&zst[tn & 1][0] + (size_t)tid * 16);
        }
        if (sl == 0) {
            #pragma unroll
            for (int i = 0; i < 16; ++i)
                #pragma unroll
                for (int j = 0; j < 8; ++j) acc[i][j] = 0.0f;
        }
        // compute: 4 q-groups x (8 wf conflict-free b128 + 4 zf broadcast b128
        // + 512 fmaf/thread)
        const float*  zb  = &zst[h][0];
        const float4* wb4 = (const float4*)&wst[h][0];
        __builtin_amdgcn_s_setprio(1);
        #pragma clang loop unroll(disable)
        for (int q = 0; q < 4; ++q) {
            const float4* wp = wb4 + q * 64 + lane;       // + j*256 (imm j*4096B)
            float4 wf[8];
            #pragma unroll
            for (int j = 0; j < 8; ++j) wf[j] = wp[j * 256];
            #pragma unroll
            for (int dp = 0; dp < 4; ++dp) {
                const float4* zp4 = (const float4*)(zb + (q * 4 + dp) * 128 + wid * 16);
                const float4 za = zp4[0], zc = zp4[1], ze = zp4[2], zg = zp4[3];
                #pragma unroll
                for (int j = 0; j < 8; ++j) {
                    const float wv = dp == 0 ? wf[j].x : dp == 1 ? wf[j].y
                                   : dp == 2 ? wf[j].z : wf[j].w;
                    acc[0][j]  = fmaf(za.x, wv, acc[0][j]);
                    acc[1][j]  = fmaf(za.y, wv, acc[1][j]);
                    acc[2][j]  = fmaf(za.z, wv, acc[2][j]);
                    acc[3][j]  = fmaf(za.w, wv, acc[3][j]);
                    acc[4][j]  = fmaf(zc.x, wv, acc[4][j]);
                    acc[5][j]  = fmaf(zc.y, wv, acc[5][j]);
                    acc[6][j]  = fmaf(zc.z, wv, acc[6][j]);
                    acc[7][j]  = fmaf(zc.w, wv, acc[7][j]);
                    acc[8][j]  = fmaf(ze.x, wv, acc[8][j]);
                    acc[9][j]  = fmaf(ze.y, wv, acc[9][j]);
                    acc[10][j] = fmaf(ze.z, wv, acc[10][j]);
                    acc[11][j] = fmaf(ze.w, wv, acc[11][j]);
                    acc[12][j] = fmaf(zg.x, wv, acc[12][j]);
                    acc[13][j] = fmaf(zg.y, wv, acc[13][j]);
                    acc[14][j] = fmaf(zg.z, wv, acc[14][j]);
                    acc[15][j] = fmaf(zg.w, wv, acc[15][j]);
                }
            }
        }
        __builtin_amdgcn_s_setprio(0);
        if (sl == 15) {
            // score + running argmin (thread codes j*64+lane: j asc = code asc;
            // strict < -> first-min like np.argmin)
            float wq[8];
            #pragma unroll
            for (int j = 0; j < 8; ++j) wq[j] = wsq[ch * 512 + j * 64 + lane];
            #pragma unroll
            for (int i = 0; i < 16; ++i) {
                const float rs = rsql[wid * 16 + i];
                #pragma unroll
                for (int j = 0; j < 8; ++j) {
                    const float s1 = rs + wq[j];             // rounding 1 (np A+B)
                    const float v = fmaf(-2.0f, acc[i][j], s1); // rounding 2 (np (A+B)-2P)
                    if (v < minv[i]) { minv[i] = v; mini[i] = ch * 512 + j * 64 + lane; }
                }
            }
        }
    }

    // ---- per-wave argmin reduce over 64 lanes (explicit index tie-break -> lowest)
    __syncthreads();                     // compute done; zst/wst become scratch
    int* idxs = (int*)&zst[0][0];        // 128 ints
    float* ssescr = (float*)&wst[0][0];  // 8 floats
    #pragma unroll
    for (int i = 0; i < 16; ++i) {
        float v = minv[i]; int ix = mini[i];
        #pragma unroll
        for (int m = 1; m < 64; m <<= 1) {
            float ov = __shfl_xor(v, m);
            int   oi = __shfl_xor(ix, m);
            if (ov < v || (ov == v && oi < ix)) { v = ov; ix = oi; }
        }
        if (lane == 0) {
            idxs[wid * 16 + i] = ix;
            atomicAdd(&counts[ix], 1);
        }
    }
    __syncthreads();

    // ---- fused gather / straight-through / SSE over 128 rows x 256 d
    const int tg = tid & 31;       // 32 t-groups of 4 rows
    const int dg = tid >> 5;       // 16 d-groups of 16
    const int t4 = tg * 4;
    int ixs[4];
    #pragma unroll
    for (int m = 0; m < 4; ++m) ixs[m] = idxs[t4 + m];
    float ssel = 0.0f;
    #pragma unroll
    for (int k4 = 0; k4 < 4; ++k4) {
        const int d0 = dg * 16 + k4 * 4;
        float wr[4][4];
        #pragma unroll
        for (int m = 0; m < 4; ++m) {
            float4 wv = *(const float4*)(W + (size_t)ixs[m] * DD + d0);
            wr[m][0] = wv.x; wr[m][1] = wv.y; wr[m][2] = wv.z; wr[m][3] = wv.w;
        }
        #pragma unroll
        for (int dd = 0; dd < 4; ++dd) {
            const int d = d0 + dd;
            const size_t base = bbase + (size_t)d * TT + t0 + t4;
            float4 zv = *(const float4*)(z + base);
            float e0 = wr[0][dd] - zv.x, e1 = wr[1][dd] - zv.y;
            float e2 = wr[2][dd] - zv.z, e3 = wr[3][dd] - zv.w;
            float4 o;
            o.x = zv.x + e0; o.y = zv.y + e1; o.z = zv.z + e2; o.w = zv.w + e3;
            *(float4*)(out + base) = o;
            ssel += (e0 * e0 + e1 * e1) + (e2 * e2 + e3 * e3);
        }
    }
    #pragma unroll
    for (int m = 32; m > 0; m >>= 1) ssel += __shfl_down(ssel, m);
    if (lane == 0) ssescr[wid] = ssel;
    __syncthreads();
    if (tid == 0)
        atomicAdd(sse, ((ssescr[0] + ssescr[1]) + (ssescr[2] + ssescr[3]))
                     + ((ssescr[4] + ssescr[5]) + (ssescr[6] + ssescr[7])));
}

// reg_loss = 1.25 * sse / numel ; perplexity = exp(-sum p*log(p+1e-10))
__global__ void finalize_kernel(const int* __restrict__ counts, const float* __restrict__ sse,
                                float* __restrict__ out) {
    float s = 0.0f;
    for (int k = threadIdx.x; k < KK; k += 256) {
        float p = (float)counts[k] / (float)NN;
        s += p * logf(p + 1e-10f);
    }
    #pragma unroll
    for (int m = 32; m > 0; m >>= 1) s += __shfl_down(s, m);
    __shared__ float wsum[4];
    if ((threadIdx.x & 63) == 0) wsum[threadIdx.x >> 6] = s;
    __syncthreads();
    if (threadIdx.x == 0) {
        float ent = (wsum[0] + wsum[1]) + (wsum[2] + wsum[3]);
        out[(size_t)BB * DD * TT]     = 1.25f * (*sse) / (float)(BB * DD * TT);
        out[(size_t)BB * DD * TT + 1] = expf(-ent);
    }
}

extern "C" void kernel_launch(void* const* d_in, const int* in_sizes, int n_in,
                              void* d_out, int out_size, void* d_ws, size_t ws_size,
                              hipStream_t stream) {
    const float* z = (const float*)d_in[0];   // (32, 256, 1024) fp32
    const float* W = (const float*)d_in[1];   // (1024, 256) fp32
    float* out = (float*)d_out;               // 8388608 + 2 fp32

    float* wsq    = (float*)d_ws;
    int*   counts = (int*)(wsq + 1024);
    float* sse    = (float*)(counts + 1024);

    prep_kernel<<<1024, 64, 0, stream>>>(W, wsq, counts, sse);
    vq_fused_kernel<<<NN / BROWS, 512, 0, stream>>>(z, W, wsq, out, counts, sse);
    finalize_kernel<<<1, 256, 0, stream>>>(counts, sse, out);
}

// Round 17
// 225.359 us; speedup vs baseline: 1.2862x; 1.0113x over previous
//
#include <hip/hip_runtime.h>
#include <math.h>

// Problem dims (fixed by reference)
#define BB 32
#define DD 256
#define TT 1024
#define KK 1024
#define NN (BB*TT)          // 32768 rows

#define BROWS 128           // rows per block (one block per CU)
#define NSTEP 32            // 2 code-chunks x 16 slices of 16 d

// ws layout (elements): float wsq[1024] @0 ; int counts[1024] @1024 ; float sse @2048

// wsq[k] = sum_d W[k,d]^2 (fp64 accumulate, round once). Zeroes counts+sse.
__global__ void prep_kernel(const float* __restrict__ W, float* __restrict__ wsq,
                            int* __restrict__ counts, float* __restrict__ sse) {
    const int k = blockIdx.x;          // 1024 blocks, 64 threads
    const int lane = threadIdx.x;
    const float4 v = ((const float4*)(W + (size_t)k * DD))[lane];
    double s = (double)v.x * v.x + (double)v.y * v.y + (double)v.z * v.z + (double)v.w * v.w;
    #pragma unroll
    for (int m = 32; m > 0; m >>= 1) s += __shfl_down(s, m);
    if (lane == 0) wsq[k] = (float)s;
    if (blockIdx.x < 16) counts[blockIdx.x * 64 + lane] = 0;
    if (blockIdx.x == 0 && lane == 0) *sse = 0.0f;
}

// async global->LDS, 16B/lane; LDS dest = wave-uniform base + lane*16 (linear).
__device__ __forceinline__ void gl_lds16(const float* g, void* l) {
    __builtin_amdgcn_global_load_lds((const __attribute__((address_space(1))) void*)g,
                                     (__attribute__((address_space(3))) void*)l, 16, 0, 0);
}

// Fused VQ — R12 optimum + ONE isolated change: q-loop unroll_count(2)
// (scheduler may overlap q's FMA with q+1's LDS reads; R13 tested this only
// bundled with a harmful rowsq-fold). Everything else identical to R12/R16
// (227.9 us, absmax==0.0, SQ_LDS_BANK_CONFLICT==0, no spill).
// 512 thr = 8 waves, 1 block/CU (grid 256), 2 waves/SIMD.
// Tile: wave wid owns rows wid*16..+15; lane owns codes {j*64+lane} of the
// current 512-code chunk -> per-thread 16x8 acc (21.3 fmaf/LDS-read).
//  - zst[2][16 d][128 r] (2x8 KB, gl_lds direct): zf reads wave-broadcast.
//  - wst[2] slot-major [j(8)][q(4)][lane(64)] (2x32 KB): conflict-free b128;
//    gl_lds linear dest + inverse-mapped source (W is L2-resident).
// dist mirrors np: s1 = fl(rowsq+wsq); v = fmaf(-2, dot, s1). Per-(row,code)
// dot: single sequential fmaf chain d=0..255 (t asc -> q asc -> dp asc) —
// bitwise-matches BLAS k-order; validated absmax==0.0 in R1-R16. DO NOT
// reorder. acc static-indexed only (rule #20). Unrolling interleaves
// independent chains without reordering any single chain (numerics-safe).
// VGPR canary: WRITE_SIZE must stay ~33.8 MB (R4/R14 spill lesson).
__global__ __launch_bounds__(512, 2) void vq_fused_kernel(
    const float* __restrict__ z, const float* __restrict__ W,
    const float* __restrict__ wsq, float* __restrict__ out,
    int* __restrict__ counts, float* __restrict__ sse)
{
    __shared__ float zst[2][16 * 128];   // 16 KB (zst[0] reused as idx scratch at end)
    __shared__ float wst[2][16 * 512];   // 64 KB (wst[0] reused as sse scratch at end)
    __shared__ float rsql[128];
    const int tid = threadIdx.x;
    const int wid = tid >> 6, lane = tid & 63;
    const int row0 = blockIdx.x * BROWS;
    const int b = row0 >> 10, t0 = row0 & 1023;
    const size_t bbase = (size_t)b * DD * TT;
    const float* zbase = z + bbase + t0;

    // ---- prologue staging for step 0 (ch=0, sl=0); latency hides under rowsq
    {
        char* dw = (char*)&wst[0][0];
        #pragma unroll
        for (int k = 0; k < 4; ++k) {
            const int m = k * 512 + tid;                  // 16B slot index
            const int j = m >> 8, q = (m >> 6) & 3, l = m & 63;
            gl_lds16(W + (size_t)(j * 64 + l) * DD + q * 4, dw + (size_t)m * 16);
        }
        const int d = tid >> 5, r4 = (tid & 31) * 4;
        gl_lds16(zbase + (size_t)d * TT + r4, (char*)&zst[0][0] + (size_t)tid * 16);
    }

    // ---- rowsq: per row 4 fp64 64-d chains, tree (p0+p1)+(p2+p3) (validated form)
    {
        double* pscr = (double*)&zst[1][0];        // 4 KB scratch (zst[1] free pre-loop)
        const int rr = tid & 127, g = tid >> 7;
        const float* zp = zbase + (size_t)g * 64 * TT + rr;
        double s = 0.0;
        #pragma unroll 4
        for (int d = 0; d < 64; ++d) { float v = zp[(size_t)d * TT]; s += (double)v * v; }
        pscr[g * 128 + rr] = s;
        __syncthreads();
        if (tid < 128)
            rsql[tid] = (float)((pscr[tid] + pscr[128 + tid]) + (pscr[256 + tid] + pscr[384 + tid]));
    }

    float minv[16]; int mini[16];
    #pragma unroll
    for (int i = 0; i < 16; ++i) { minv[i] = 3.4e38f; mini[i] = 0; }
    float acc[16][8];

    for (int t = 0; t < NSTEP; ++t) {
        const int ch = t >> 4, sl = t & 15, h = t & 1;
        __syncthreads();   // drains vmcnt/lgkm: buffers[h] (staged at t-1) ready;
                           // at t=0 also fences rowsq scratch in zst[1]
        // issue step t+1 staging NOW; lands during ~8192 cyc of compute below
        if (t + 1 < NSTEP) {
            const int tn = t + 1, chn = tn >> 4, sln = tn & 15;
            const float* wc = W + (size_t)(chn * 512) * DD + sln * 16;
            char* dw = (char*)&wst[tn & 1][0];
            #pragma unroll
            for (int k = 0; k < 4; ++k) {
                const int m = k * 512 + tid;
                const int j = m >> 8, q = (m >> 6) & 3, l = m & 63;
                gl_lds16(wc + (size_t)(j * 64 + l) * DD + q * 4, dw + (size_t)m * 16);
            }
            const int d = tid >> 5, r4 = (tid & 31) * 4;
            gl_lds16(zbase + (size_t)(sln * 16 + d) * TT + r4,
                     (char*)&zst[tn & 1][0] + (size_t)tid * 16);
        }
        if (sl == 0) {
            #pragma unroll
            for (int i = 0; i < 16; ++i)
                #pragma unroll
                for (int j = 0; j < 8; ++j) acc[i][j] = 0.0f;
        }
        // compute: 4 q-groups x (8 wf conflict-free b128 + 4 zf broadcast b128
        // + 2048 fmaf/thread/step); unroll_count(2) overlaps q / q+1
        const float*  zb  = &zst[h][0];
        const float4* wb4 = (const float4*)&wst[h][0];
        __builtin_amdgcn_s_setprio(1);
        #pragma clang loop unroll_count(2)
        for (int q = 0; q < 4; ++q) {
            const float4* wp = wb4 + q * 64 + lane;       // + j*256 (imm j*4096B)
            float4 wf[8];
            #pragma unroll
            for (int j = 0; j < 8; ++j) wf[j] = wp[j * 256];
            #pragma unroll
            for (int dp = 0; dp < 4; ++dp) {
                const float4* zp4 = (const float4*)(zb + (q * 4 + dp) * 128 + wid * 16);
                const float4 za = zp4[0], zc = zp4[1], ze = zp4[2], zg = zp4[3];
                #pragma unroll
                for (int j = 0; j < 8; ++j) {
                    const float wv = dp == 0 ? wf[j].x : dp == 1 ? wf[j].y
                                   : dp == 2 ? wf[j].z : wf[j].w;
                    acc[0][j]  = fmaf(za.x, wv, acc[0][j]);
                    acc[1][j]  = fmaf(za.y, wv, acc[1][j]);
                    acc[2][j]  = fmaf(za.z, wv, acc[2][j]);
                    acc[3][j]  = fmaf(za.w, wv, acc[3][j]);
                    acc[4][j]  = fmaf(zc.x, wv, acc[4][j]);
                    acc[5][j]  = fmaf(zc.y, wv, acc[5][j]);
                    acc[6][j]  = fmaf(zc.z, wv, acc[6][j]);
                    acc[7][j]  = fmaf(zc.w, wv, acc[7][j]);
                    acc[8][j]  = fmaf(ze.x, wv, acc[8][j]);
                    acc[9][j]  = fmaf(ze.y, wv, acc[9][j]);
                    acc[10][j] = fmaf(ze.z, wv, acc[10][j]);
                    acc[11][j] = fmaf(ze.w, wv, acc[11][j]);
                    acc[12][j] = fmaf(zg.x, wv, acc[12][j]);
                    acc[13][j] = fmaf(zg.y, wv, acc[13][j]);
                    acc[14][j] = fmaf(zg.z, wv, acc[14][j]);
                    acc[15][j] = fmaf(zg.w, wv, acc[15][j]);
                }
            }
        }
        __builtin_amdgcn_s_setprio(0);
        if (sl == 15) {
            // score + running argmin (thread codes j*64+lane: j asc = code asc;
            // strict < -> first-min like np.argmin)
            float wq[8];
            #pragma unroll
            for (int j = 0; j < 8; ++j) wq[j] = wsq[ch * 512 + j * 64 + lane];
            #pragma unroll
            for (int i = 0; i < 16; ++i) {
                const float rs = rsql[wid * 16 + i];
                #pragma unroll
                for (int j = 0; j < 8; ++j) {
                    const float s1 = rs + wq[j];             // rounding 1 (np A+B)
                    const float v = fmaf(-2.0f, acc[i][j], s1); // rounding 2 (np (A+B)-2P)
                    if (v < minv[i]) { minv[i] = v; mini[i] = ch * 512 + j * 64 + lane; }
                }
            }
        }
    }

    // ---- per-wave argmin reduce over 64 lanes (explicit index tie-break -> lowest)
    __syncthreads();                     // compute done; zst/wst become scratch
    int* idxs = (int*)&zst[0][0];        // 128 ints
    float* ssescr = (float*)&wst[0][0];  // 8 floats
    #pragma unroll
    for (int i = 0; i < 16; ++i) {
        float v = minv[i]; int ix = mini[i];
        #pragma unroll
        for (int m = 1; m < 64; m <<= 1) {
            float ov = __shfl_xor(v, m);
            int   oi = __shfl_xor(ix, m);
            if (ov < v || (ov == v && oi < ix)) { v = ov; ix = oi; }
        }
        if (lane == 0) {
            idxs[wid * 16 + i] = ix;
            atomicAdd(&counts[ix], 1);
        }
    }
    __syncthreads();

    // ---- fused gather / straight-through / SSE over 128 rows x 256 d
    const int tg = tid & 31;       // 32 t-groups of 4 rows
    const int dg = tid >> 5;       // 16 d-groups of 16
    const int t4 = tg * 4;
    int ixs[4];
    #pragma unroll
    for (int m = 0; m < 4; ++m) ixs[m] = idxs[t4 + m];
    float ssel = 0.0f;
    #pragma unroll
    for (int k4 = 0; k4 < 4; ++k4) {
        const int d0 = dg * 16 + k4 * 4;
        float wr[4][4];
        #pragma unroll
        for (int m = 0; m < 4; ++m) {
            float4 wv = *(const float4*)(W + (size_t)ixs[m] * DD + d0);
            wr[m][0] = wv.x; wr[m][1] = wv.y; wr[m][2] = wv.z; wr[m][3] = wv.w;
        }
        #pragma unroll
        for (int dd = 0; dd < 4; ++dd) {
            const int d = d0 + dd;
            const size_t base = bbase + (size_t)d * TT + t0 + t4;
            float4 zv = *(const float4*)(z + base);
            float e0 = wr[0][dd] - zv.x, e1 = wr[1][dd] - zv.y;
            float e2 = wr[2][dd] - zv.z, e3 = wr[3][dd] - zv.w;
            float4 o;
            o.x = zv.x + e0; o.y = zv.y + e1; o.z = zv.z + e2; o.w = zv.w + e3;
            *(float4*)(out + base) = o;
            ssel += (e0 * e0 + e1 * e1) + (e2 * e2 + e3 * e3);
        }
    }
    #pragma unroll
    for (int m = 32; m > 0; m >>= 1) ssel += __shfl_down(ssel, m);
    if (lane == 0) ssescr[wid] = ssel;
    __syncthreads();
    if (tid == 0)
        atomicAdd(sse, ((ssescr[0] + ssescr[1]) + (ssescr[2] + ssescr[3]))
                     + ((ssescr[4] + ssescr[5]) + (ssescr[6] + ssescr[7])));
}

// reg_loss = 1.25 * sse / numel ; perplexity = exp(-sum p*log(p+1e-10))
__global__ void finalize_kernel(const int* __restrict__ counts, const float* __restrict__ sse,
                                float* __restrict__ out) {
    float s = 0.0f;
    for (int k = threadIdx.x; k < KK; k += 256) {
        float p = (float)counts[k] / (float)NN;
        s += p * logf(p + 1e-10f);
    }
    #pragma unroll
    for (int m = 32; m > 0; m >>= 1) s += __shfl_down(s, m);
    __shared__ float wsum[4];
    if ((threadIdx.x & 63) == 0) wsum[threadIdx.x >> 6] = s;
    __syncthreads();
    if (threadIdx.x == 0) {
        float ent = (wsum[0] + wsum[1]) + (wsum[2] + wsum[3]);
        out[(size_t)BB * DD * TT]     = 1.25f * (*sse) / (float)(BB * DD * TT);
        out[(size_t)BB * DD * TT + 1] = expf(-ent);
    }
}

extern "C" void kernel_launch(void* const* d_in, const int* in_sizes, int n_in,
                              void* d_out, int out_size, void* d_ws, size_t ws_size,
                              hipStream_t stream) {
    const float* z = (const float*)d_in[0];   // (32, 256, 1024) fp32
    const float* W = (const float*)d_in[1];   // (1024, 256) fp32
    float* out = (float*)d_out;               // 8388608 + 2 fp32

    float* wsq    = (float*)d_ws;
    int*   counts = (int*)(wsq + 1024);
    float* sse    = (float*)(counts + 1024);

    prep_kernel<<<1024, 64, 0, stream>>>(W, wsq, counts, sse);
    vq_fused_kernel<<<NN / BROWS, 512, 0, stream>>>(z, W, wsq, out, counts, sse);
    finalize_kernel<<<1, 256, 0, stream>>>(counts, sse, out);
}